// Round 1
// baseline (578.334 us; speedup 1.0000x reference)
//
#include <hip/hip_runtime.h>
#include <math.h>

// Problem constants (fixed by setup_inputs): B=2,S=2048 -> T=4096, H=768, E=8, F=3072, K=2, BLOCK=16
#define T_TOK 4096
#define H_DIM 768
#define E_NUM 8
#define F_DIM 3072
#define EF_DIM 24576   // E*F
#define BK 32
#define LDK 40         // LDS leading dim in halves (32 + 8 pad -> 80B rows, 16B-aligned, 2-way conflicts only)
#define MAX_TILES 72   // max sum over experts of ceil(count_e/128) = 64 + 7 (+1 slack)

// ws meta layout (int offsets)
#define OFF_COUNT   0
#define OFF_CURSOR  8
#define OFF_LAST    16   // stores flat_idx+1 (atomicMax vs zeroed init)
#define OFF_PAD     24
#define OFF_SEG     32
#define OFF_NT      40
#define OFF_SCHED_E 48
#define OFF_SCHED_G 120
// meta ends at 192 ints = 768 bytes
#define WS_SEL   768                        // int sel[8192]
#define WS_TOK   33536                      // int tok[9216]
#define WS_COEF  70400                      // float coefv[9216]
#define WS_HG    107264                     // bf16 hg[9216][3072]  (~56.6 MB), 16B aligned

typedef __attribute__((ext_vector_type(8))) short short8;
typedef __attribute__((ext_vector_type(4))) short short4v;
typedef __attribute__((ext_vector_type(4))) float float4v;

__device__ __forceinline__ short f2b(float f) {
  union { float f; unsigned u; } v; v.f = f;
  unsigned r = v.u + 0x7FFFu + ((v.u >> 16) & 1u);  // round-to-nearest-even
  return (short)(r >> 16);
}
__device__ __forceinline__ float gelu_exact(float v) {
  return 0.5f * v * (1.0f + erff(v * 0.70710678118654752f));
}

// ---------------- Router: logits (fp64 accum), top-2, counts/last atomics ----------------
__global__ __launch_bounds__(256) void router_k(const float* __restrict__ x,
                                                const float* __restrict__ rw,
                                                float* __restrict__ logits_out,
                                                int* __restrict__ meta,
                                                int* __restrict__ sel) {
  __shared__ float rws[E_NUM * H_DIM];
  for (int i = threadIdx.x; i < E_NUM * H_DIM; i += 256) rws[i] = rw[i];
  __syncthreads();
  const int wid = threadIdx.x >> 6, lane = threadIdx.x & 63;
  const int t = blockIdx.x * 4 + wid;
  const float* xr = x + (size_t)t * H_DIM;
  double acc[E_NUM];
#pragma unroll
  for (int e = 0; e < E_NUM; ++e) acc[e] = 0.0;
  for (int i = 0; i < H_DIM / 64; ++i) {
    const int h = lane + 64 * i;
    const float xv = xr[h];
#pragma unroll
    for (int e = 0; e < E_NUM; ++e) acc[e] += (double)xv * (double)rws[e * H_DIM + h];
  }
#pragma unroll
  for (int e = 0; e < E_NUM; ++e)
    for (int off = 32; off; off >>= 1) acc[e] += __shfl_down(acc[e], off);
  if (lane == 0) {
    float lg[E_NUM];
#pragma unroll
    for (int e = 0; e < E_NUM; ++e) { lg[e] = (float)acc[e]; logits_out[t * E_NUM + e] = lg[e]; }
    int e0 = 0;
    for (int e = 1; e < E_NUM; ++e) if (lg[e] > lg[e0]) e0 = e;       // ties -> lowest idx
    int e1 = -1;
    for (int e = 0; e < E_NUM; ++e) {
      if (e == e0) continue;
      if (e1 < 0 || lg[e] > lg[e1]) e1 = e;
    }
    sel[t * 2 + 0] = e0;
    sel[t * 2 + 1] = e1;
    atomicAdd(&meta[OFF_COUNT + e0], 1);
    atomicAdd(&meta[OFF_COUNT + e1], 1);
    atomicMax(&meta[OFF_LAST + e0], t * 2 + 0 + 1);
    atomicMax(&meta[OFF_LAST + e1], t * 2 + 1 + 1);
  }
}

// ---------------- Schedule: pad, segment starts, M-tile schedule, pad-slot init ----------------
__global__ void schedule_k(int* __restrict__ meta, int* __restrict__ tok, float* __restrict__ coefv) {
  int cnt[E_NUM], seg[E_NUM];
  int s = 0;
#pragma unroll
  for (int e = 0; e < E_NUM; ++e) cnt[e] = meta[OFF_COUNT + e];
#pragma unroll
  for (int e = 0; e < E_NUM; ++e) { seg[e] = s; s += (cnt[e] + 127) & ~127; }
  if (threadIdx.x == 0) {
    int nt = 0;
    for (int e = 0; e < E_NUM; ++e) {
      meta[OFF_PAD + e] = (16 - (cnt[e] & 15)) & 15;
      meta[OFF_SEG + e] = seg[e];
      const int ru = (cnt[e] + 127) & ~127;
      for (int m = 0; m < ru; m += 128) {
        meta[OFF_SCHED_E + nt] = e;
        meta[OFF_SCHED_G + nt] = seg[e] + m;
        ++nt;
      }
    }
    meta[OFF_NT] = nt;
  }
  // fill padding slots (rows in [cnt, roundup128)): tok=-1, coef=0
  for (int e = 0; e < E_NUM; ++e) {
    const int ru = (cnt[e] + 127) & ~127;
    for (int p = cnt[e] + (int)threadIdx.x; p < ru; p += 64) {
      tok[seg[e] + p] = -1;
      coefv[seg[e] + p] = 0.0f;
    }
  }
}

// ---------------- Scatter: build gathered token list + coef per slot ----------------
__global__ __launch_bounds__(256) void scatter_k(const int* __restrict__ sel,
                                                 int* __restrict__ meta,
                                                 int* __restrict__ tok,
                                                 float* __restrict__ coefv) {
  const int a = blockIdx.x * 256 + threadIdx.x;  // assignment id in [0, T*K)
  const int e = sel[a];
  const int p = atomicAdd(&meta[OFF_CURSOR + e], 1);
  const int g = meta[OFF_SEG + e] + p;
  tok[g] = a >> 1;
  coefv[g] = (meta[OFF_LAST + e] == a + 1) ? (float)(1 + meta[OFF_PAD + e]) : 1.0f;
}

// ---------------- GEMM1: Hg = gelu(Xg @ W1e), bf16 MFMA, 128x128 tile ----------------
__global__ __launch_bounds__(256) void gemm1_k(const float* __restrict__ x,
                                               const float* __restrict__ w1,
                                               const int* __restrict__ meta,
                                               const int* __restrict__ tok,
                                               short* __restrict__ hg) {
  const int slot = blockIdx.y;
  if (slot >= meta[OFF_NT]) return;
  const int e = meta[OFF_SCHED_E + slot];
  const int gbase = meta[OFF_SCHED_G + slot];
  const int n0 = blockIdx.x * 128;  // within F

  __shared__ short As[128 * LDK];
  __shared__ short Bs[128 * LDK];

  const int tid = threadIdx.x;
  // A staging: thread -> (row, 16-col half)
  const int ar = tid >> 1;
  const int ak = (tid & 1) * 16;
  const int trow = tok[gbase + ar];
  const float* xrow = x + (size_t)(trow < 0 ? 0 : trow) * H_DIM;
  // B staging: thread -> 4 k-rows x 4 n-cols micro-transpose
  const int bk = (tid >> 5) * 4;
  const int bn = (tid & 31) * 4;
  // MFMA layout
  const int wid = tid >> 6, lane = tid & 63;
  const int mw = (wid & 1) * 64, nw = (wid >> 1) * 64;
  const int lrow = lane & 15, q = lane >> 4;

  float4v acc[4][4] = {};

  for (int k0 = 0; k0 < H_DIM; k0 += BK) {
    // stage A (gathered x rows, fp32 -> bf16)
    {
      const float* src = xrow + k0 + ak;
      float4v f0 = *(const float4v*)(src);
      float4v f1 = *(const float4v*)(src + 4);
      float4v f2 = *(const float4v*)(src + 8);
      float4v f3 = *(const float4v*)(src + 12);
      short8 s0 = { f2b(f0[0]), f2b(f0[1]), f2b(f0[2]), f2b(f0[3]),
                    f2b(f1[0]), f2b(f1[1]), f2b(f1[2]), f2b(f1[3]) };
      short8 s1 = { f2b(f2[0]), f2b(f2[1]), f2b(f2[2]), f2b(f2[3]),
                    f2b(f3[0]), f2b(f3[1]), f2b(f3[2]), f2b(f3[3]) };
      *(short8*)(&As[ar * LDK + ak]) = s0;
      *(short8*)(&As[ar * LDK + ak + 8]) = s1;
    }
    // stage B (W1e, n-contig global -> k-contig transposed LDS)
    {
      float4v row[4];
#pragma unroll
      for (int kk = 0; kk < 4; ++kk)
        row[kk] = *(const float4v*)(w1 + (size_t)(k0 + bk + kk) * EF_DIM + e * F_DIM + n0 + bn);
#pragma unroll
      for (int nn = 0; nn < 4; ++nn) {
        short4v sv = { f2b(row[0][nn]), f2b(row[1][nn]), f2b(row[2][nn]), f2b(row[3][nn]) };
        *(short4v*)(&Bs[(bn + nn) * LDK + bk]) = sv;
      }
    }
    __syncthreads();
    short8 a_frag[4], b_frag[4];
#pragma unroll
    for (int i = 0; i < 4; ++i) a_frag[i] = *(const short8*)(&As[(mw + 16 * i + lrow) * LDK + q * 8]);
#pragma unroll
    for (int j = 0; j < 4; ++j) b_frag[j] = *(const short8*)(&Bs[(nw + 16 * j + lrow) * LDK + q * 8]);
#pragma unroll
    for (int i = 0; i < 4; ++i)
#pragma unroll
      for (int j = 0; j < 4; ++j)
        acc[i][j] = __builtin_amdgcn_mfma_f32_16x16x32_bf16(a_frag[i], b_frag[j], acc[i][j], 0, 0, 0);
    __syncthreads();
  }
  // epilogue: gelu + bf16 store to Hg
#pragma unroll
  for (int i = 0; i < 4; ++i) {
#pragma unroll
    for (int j = 0; j < 4; ++j) {
#pragma unroll
      for (int r = 0; r < 4; ++r) {
        const int row = mw + 16 * i + q * 4 + r;
        const int col = nw + 16 * j + lrow;
        hg[(size_t)(gbase + row) * F_DIM + n0 + col] = f2b(gelu_exact(acc[i][j][r]));
      }
    }
  }
}

// ---------------- GEMM2: out[tok] += coef * (Hg @ W2e), atomic scatter ----------------
__global__ __launch_bounds__(256) void gemm2_k(const short* __restrict__ hg,
                                               const float* __restrict__ w2,
                                               const int* __restrict__ meta,
                                               const int* __restrict__ tok,
                                               const float* __restrict__ coefv,
                                               float* __restrict__ out) {
  const int slot = blockIdx.y;
  if (slot >= meta[OFF_NT]) return;
  const int e = meta[OFF_SCHED_E + slot];
  const int gbase = meta[OFF_SCHED_G + slot];
  const int n0 = blockIdx.x * 128;  // within H

  __shared__ short As[128 * LDK];
  __shared__ short Bs[128 * LDK];

  const int tid = threadIdx.x;
  const int ar = tid >> 1;
  const int ak = (tid & 1) * 16;
  const short* hrow = hg + (size_t)(gbase + ar) * F_DIM;
  const int bk = (tid >> 5) * 4;
  const int bn = (tid & 31) * 4;
  const int wid = tid >> 6, lane = tid & 63;
  const int mw = (wid & 1) * 64, nw = (wid >> 1) * 64;
  const int lrow = lane & 15, q = lane >> 4;

  float4v acc[4][4] = {};

  for (int k0 = 0; k0 < F_DIM; k0 += BK) {
    // stage A (Hg, already bf16, k-contig)
    {
      short8 s0 = *(const short8*)(hrow + k0 + ak);
      short8 s1 = *(const short8*)(hrow + k0 + ak + 8);
      *(short8*)(&As[ar * LDK + ak]) = s0;
      *(short8*)(&As[ar * LDK + ak + 8]) = s1;
    }
    // stage B (W2e, n-contig global -> k-contig transposed LDS)
    {
      float4v row[4];
#pragma unroll
      for (int kk = 0; kk < 4; ++kk)
        row[kk] = *(const float4v*)(w2 + (size_t)(e * F_DIM + k0 + bk + kk) * H_DIM + n0 + bn);
#pragma unroll
      for (int nn = 0; nn < 4; ++nn) {
        short4v sv = { f2b(row[0][nn]), f2b(row[1][nn]), f2b(row[2][nn]), f2b(row[3][nn]) };
        *(short4v*)(&Bs[(bn + nn) * LDK + bk]) = sv;
      }
    }
    __syncthreads();
    short8 a_frag[4], b_frag[4];
#pragma unroll
    for (int i = 0; i < 4; ++i) a_frag[i] = *(const short8*)(&As[(mw + 16 * i + lrow) * LDK + q * 8]);
#pragma unroll
    for (int j = 0; j < 4; ++j) b_frag[j] = *(const short8*)(&Bs[(nw + 16 * j + lrow) * LDK + q * 8]);
#pragma unroll
    for (int i = 0; i < 4; ++i)
#pragma unroll
      for (int j = 0; j < 4; ++j)
        acc[i][j] = __builtin_amdgcn_mfma_f32_16x16x32_bf16(a_frag[i], b_frag[j], acc[i][j], 0, 0, 0);
    __syncthreads();
  }
  // epilogue: coef-scaled atomic scatter-add into out
#pragma unroll
  for (int i = 0; i < 4; ++i) {
#pragma unroll
    for (int r = 0; r < 4; ++r) {
      const int row = mw + 16 * i + q * 4 + r;
      const int g = gbase + row;
      const int t = tok[g];
      if (t < 0) continue;
      const float cf = coefv[g];
#pragma unroll
      for (int j = 0; j < 4; ++j) {
        const int col = nw + 16 * j + lrow;
        atomicAdd(&out[(size_t)t * H_DIM + n0 + col], cf * acc[i][j][r]);
      }
    }
  }
}

extern "C" void kernel_launch(void* const* d_in, const int* in_sizes, int n_in,
                              void* d_out, int out_size, void* d_ws, size_t ws_size,
                              hipStream_t stream) {
  const float* x  = (const float*)d_in[0];
  const float* rw = (const float*)d_in[1];
  const float* w1 = (const float*)d_in[2];
  const float* w2 = (const float*)d_in[3];
  float* out = (float*)d_out;                         // [T, H] fp32
  float* logits = out + (size_t)T_TOK * H_DIM;        // [T, E] fp32

  char* ws = (char*)d_ws;
  int*   meta  = (int*)ws;
  int*   sel   = (int*)(ws + WS_SEL);
  int*   tok   = (int*)(ws + WS_TOK);
  float* coefv = (float*)(ws + WS_COEF);
  short* hg    = (short*)(ws + WS_HG);

  // zero accumulation target + meta counters (graph-capturable async memsets)
  hipMemsetAsync(d_out, 0, (size_t)T_TOK * H_DIM * sizeof(float), stream);
  hipMemsetAsync(ws, 0, 768, stream);

  router_k<<<T_TOK / 4, 256, 0, stream>>>(x, rw, logits, meta, sel);
  schedule_k<<<1, 64, 0, stream>>>(meta, tok, coefv);
  scatter_k<<<(T_TOK * 2) / 256, 256, 0, stream>>>(sel, meta, tok, coefv);
  gemm1_k<<<dim3(F_DIM / 128, MAX_TILES), 256, 0, stream>>>(x, w1, meta, tok, hg);
  gemm2_k<<<dim3(H_DIM / 128, MAX_TILES), 256, 0, stream>>>(hg, w2, meta, tok, coefv, out);
}

// Round 2
// 557.570 us; speedup vs baseline: 1.0372x; 1.0372x over previous
//
#include <hip/hip_runtime.h>
#include <math.h>

// Problem constants: B=2,S=2048 -> T=4096, H=768, E=8, F=3072, K=2, BLOCK=16
#define T_TOK 4096
#define H_DIM 768
#define E_NUM 8
#define F_DIM 3072
#define EF_DIM 24576
#define BK 32
#define SEG_MAX 9216
#define MAX_TILES 72

// meta ints
#define OFF_COUNT   0
#define OFF_CURSOR  8
#define OFF_LAST    16
#define OFF_PAD     24
#define OFF_SEG     32
#define OFF_NT      40
#define OFF_TOTAL   41
#define OFF_SCHED_E 48
#define OFF_SCHED_G 120

// ws byte offsets
#define WS_SEL   768
#define WS_TOK   33536
#define WS_COEF  70400
#define WS_XG    107264ull     // bf16 Xg[9216][768]   = 14.16 MB
#define WS_HG    14263040ull   // bf16 Hg[9216][3072]  = 56.62 MB
#define WS_WT    70886144ull   // bf16 Wt (W1t then W2t, shared) = 37.75 MB; total ~103.6 MiB

typedef __attribute__((ext_vector_type(8))) short short8;
typedef __attribute__((ext_vector_type(4))) float float4v;

__device__ __forceinline__ short f2b(float f) {
  union { float f; unsigned u; } v; v.f = f;
  unsigned r = v.u + 0x7FFFu + ((v.u >> 16) & 1u);  // RNE
  return (short)(r >> 16);
}
__device__ __forceinline__ float gelu_exact(float v) {
  return 0.5f * v * (1.0f + erff(v * 0.70710678118654752f));
}
__device__ __forceinline__ void gl_lds16(const void* g, void* l) {
  __builtin_amdgcn_global_load_lds(
      (const __attribute__((address_space(1))) void*)g,
      (__attribute__((address_space(3))) void*)l, 16, 0, 0);
}

// ---------------- Router: logits (fp64 accum), top-2, counts/last ----------------
__global__ __launch_bounds__(256) void router_k(const float* __restrict__ x,
                                                const float* __restrict__ rw,
                                                float* __restrict__ logits_out,
                                                int* __restrict__ meta,
                                                int* __restrict__ sel) {
  __shared__ float rws[E_NUM * H_DIM];
  for (int i = threadIdx.x; i < E_NUM * H_DIM; i += 256) rws[i] = rw[i];
  __syncthreads();
  const int wid = threadIdx.x >> 6, lane = threadIdx.x & 63;
  const int t = blockIdx.x * 4 + wid;
  const float* xr = x + (size_t)t * H_DIM;
  double acc[E_NUM];
#pragma unroll
  for (int e = 0; e < E_NUM; ++e) acc[e] = 0.0;
  for (int i = 0; i < H_DIM / 64; ++i) {
    const int h = lane + 64 * i;
    const float xv = xr[h];
#pragma unroll
    for (int e = 0; e < E_NUM; ++e) acc[e] += (double)xv * (double)rws[e * H_DIM + h];
  }
#pragma unroll
  for (int e = 0; e < E_NUM; ++e)
    for (int off = 32; off; off >>= 1) acc[e] += __shfl_down(acc[e], off);
  if (lane == 0) {
    float lg[E_NUM];
#pragma unroll
    for (int e = 0; e < E_NUM; ++e) { lg[e] = (float)acc[e]; logits_out[t * E_NUM + e] = lg[e]; }
    int e0 = 0;
    for (int e = 1; e < E_NUM; ++e) if (lg[e] > lg[e0]) e0 = e;
    int e1 = -1;
    for (int e = 0; e < E_NUM; ++e) {
      if (e == e0) continue;
      if (e1 < 0 || lg[e] > lg[e1]) e1 = e;
    }
    sel[t * 2 + 0] = e0;
    sel[t * 2 + 1] = e1;
    atomicAdd(&meta[OFF_COUNT + e0], 1);
    atomicAdd(&meta[OFF_COUNT + e1], 1);
    atomicMax(&meta[OFF_LAST + e0], t * 2 + 0 + 1);
    atomicMax(&meta[OFF_LAST + e1], t * 2 + 1 + 1);
  }
}

// ---------------- Schedule ----------------
__global__ void schedule_k(int* __restrict__ meta, int* __restrict__ tok, float* __restrict__ coefv) {
  int cnt[E_NUM], seg[E_NUM];
  int s = 0;
#pragma unroll
  for (int e = 0; e < E_NUM; ++e) cnt[e] = meta[OFF_COUNT + e];
#pragma unroll
  for (int e = 0; e < E_NUM; ++e) { seg[e] = s; s += (cnt[e] + 127) & ~127; }
  if (threadIdx.x == 0) {
    int nt = 0;
    for (int e = 0; e < E_NUM; ++e) {
      meta[OFF_PAD + e] = (16 - (cnt[e] & 15)) & 15;
      meta[OFF_SEG + e] = seg[e];
      const int ru = (cnt[e] + 127) & ~127;
      for (int m = 0; m < ru; m += 128) {
        meta[OFF_SCHED_E + nt] = e;
        meta[OFF_SCHED_G + nt] = seg[e] + m;
        ++nt;
      }
    }
    meta[OFF_NT] = nt;
    meta[OFF_TOTAL] = s;
  }
  // pad slots inside segments
  for (int e = 0; e < E_NUM; ++e) {
    const int ru = (cnt[e] + 127) & ~127;
    for (int p = cnt[e] + (int)threadIdx.x; p < ru; p += 64) {
      tok[seg[e] + p] = -1;
      coefv[seg[e] + p] = 0.0f;
    }
  }
  // tail beyond all segments
  for (int p = s + (int)threadIdx.x; p < SEG_MAX; p += 64) {
    tok[p] = -1;
    coefv[p] = 0.0f;
  }
}

// ---------------- Scatter ----------------
__global__ __launch_bounds__(256) void scatter_k(const int* __restrict__ sel,
                                                 int* __restrict__ meta,
                                                 int* __restrict__ tok,
                                                 float* __restrict__ coefv) {
  const int a = blockIdx.x * 256 + threadIdx.x;
  const int e = sel[a];
  const int p = atomicAdd(&meta[OFF_CURSOR + e], 1);
  const int g = meta[OFF_SEG + e] + p;
  tok[g] = a >> 1;
  coefv[g] = (meta[OFF_LAST + e] == a + 1) ? (float)(1 + meta[OFF_PAD + e]) : 1.0f;
}

// ---------------- Gather x rows -> bf16 Xg ----------------
__global__ __launch_bounds__(256) void gather_x_k(const float* __restrict__ x,
                                                  const int* __restrict__ tok,
                                                  short* __restrict__ xg) {
  const int u = blockIdx.x * 256 + threadIdx.x;  // 9216*96 units of 8 halves
  const int g = u / 96;
  const int c = (u - g * 96) * 8;
  const int t = tok[g];
  short8 v = {0, 0, 0, 0, 0, 0, 0, 0};
  if (t >= 0) {
    const float* src = x + (size_t)t * H_DIM + c;
    float4v f0 = *(const float4v*)src;
    float4v f1 = *(const float4v*)(src + 4);
    v[0] = f2b(f0[0]); v[1] = f2b(f0[1]); v[2] = f2b(f0[2]); v[3] = f2b(f0[3]);
    v[4] = f2b(f1[0]); v[5] = f2b(f1[1]); v[6] = f2b(f1[2]); v[7] = f2b(f1[3]);
  }
  *(short8*)&xg[(size_t)g * H_DIM + c] = v;
}

// ---------------- W1 [H][EF] f32 -> W1t [EF][H] bf16 (k-contig rows) ----------------
__global__ __launch_bounds__(256) void conv_w1_k(const float* __restrict__ w1, short* __restrict__ w1t) {
  __shared__ float tile[64][65];
  const int n0 = blockIdx.x * 64;  // EF
  const int h0 = blockIdx.y * 64;  // H
  const int tid = threadIdx.x;
  const int rr = tid >> 4;
  const int cc = (tid & 15) * 4;
#pragma unroll
  for (int p = 0; p < 4; ++p) {
    const int r = p * 16 + rr;  // h-local
    float4v f = *(const float4v*)(w1 + (size_t)(h0 + r) * EF_DIM + n0 + cc);
    tile[r][cc] = f[0]; tile[r][cc + 1] = f[1]; tile[r][cc + 2] = f[2]; tile[r][cc + 3] = f[3];
  }
  __syncthreads();
#pragma unroll
  for (int p = 0; p < 2; ++p) {
    const int item = p * 256 + tid;
    const int nl = item >> 3;       // n-local 0..63
    const int u8 = (item & 7) * 8;  // h-start
    short8 v;
#pragma unroll
    for (int j = 0; j < 8; ++j) v[j] = f2b(tile[u8 + j][nl]);
    *(short8*)(w1t + (size_t)(n0 + nl) * H_DIM + h0 + u8) = v;
  }
}

// ---------------- W2 [EF][H] f32 -> W2t [E][H][F] bf16 (k-contig rows) ----------------
__global__ __launch_bounds__(256) void conv_w2_k(const float* __restrict__ w2, short* __restrict__ w2t) {
  __shared__ float tile[64][65];
  const int k0 = blockIdx.x * 64;  // EF rows
  const int h0 = blockIdx.y * 64;  // H cols
  const int e = k0 / F_DIM;
  const int f0 = k0 - e * F_DIM;
  const int tid = threadIdx.x;
  const int rr = tid >> 4;
  const int cc = (tid & 15) * 4;
#pragma unroll
  for (int p = 0; p < 4; ++p) {
    const int r = p * 16 + rr;  // f-local
    float4v f = *(const float4v*)(w2 + (size_t)(k0 + r) * H_DIM + h0 + cc);
    tile[r][cc] = f[0]; tile[r][cc + 1] = f[1]; tile[r][cc + 2] = f[2]; tile[r][cc + 3] = f[3];
  }
  __syncthreads();
#pragma unroll
  for (int p = 0; p < 2; ++p) {
    const int item = p * 256 + tid;
    const int nl = item >> 3;       // h-local 0..63
    const int u8 = (item & 7) * 8;  // f-start
    short8 v;
#pragma unroll
    for (int j = 0; j < 8; ++j) v[j] = f2b(tile[u8 + j][nl]);
    *(short8*)(w2t + (size_t)(e * H_DIM + h0 + nl) * F_DIM + f0 + u8) = v;
  }
}

// ---------------- GEMM1: Hg = gelu(Xg @ W1t^T), m97-style ----------------
__global__ __launch_bounds__(256) void gemm1_k(const short* __restrict__ xg,
                                               const short* __restrict__ w1t,
                                               const int* __restrict__ meta,
                                               short* __restrict__ hg) {
  const int slot = blockIdx.y;
  if (slot >= meta[OFF_NT]) return;
  const int e = meta[OFF_SCHED_E + slot];
  const int gbase = meta[OFF_SCHED_G + slot];
  const int n0 = blockIdx.x * 128;

  __shared__ short As[128 * BK];
  __shared__ short Bs[128 * BK];

  const int tid = threadIdx.x;
  const int w = tid >> 6, l = tid & 63;
  const int mw = (w & 1) * 64, nw = (w >> 1) * 64;
  const int lrow = l & 15, q = l >> 4;

  const int srow = l >> 2;
  const int sk = (l & 3) * 8;
  const short* ag0 = xg + (size_t)(gbase + w * 32 + srow) * H_DIM + sk;
  const short* ag1 = ag0 + 16 * H_DIM;
  const short* bg0 = w1t + (size_t)(e * F_DIM + n0 + w * 32 + srow) * H_DIM + sk;
  const short* bg1 = bg0 + 16 * H_DIM;
  short* al0 = &As[(w * 32) * BK];
  short* al1 = &As[(w * 32 + 16) * BK];
  short* bl0 = &Bs[(w * 32) * BK];
  short* bl1 = &Bs[(w * 32 + 16) * BK];

  float4v acc[4][4] = {};

  for (int k0 = 0; k0 < H_DIM; k0 += BK) {
    gl_lds16(ag0 + k0, al0);
    gl_lds16(ag1 + k0, al1);
    gl_lds16(bg0 + k0, bl0);
    gl_lds16(bg1 + k0, bl1);
    __syncthreads();
    short8 a_frag[4], b_frag[4];
#pragma unroll
    for (int i = 0; i < 4; ++i) a_frag[i] = *(const short8*)&As[(mw + 16 * i + lrow) * BK + q * 8];
#pragma unroll
    for (int j = 0; j < 4; ++j) b_frag[j] = *(const short8*)&Bs[(nw + 16 * j + lrow) * BK + q * 8];
#pragma unroll
    for (int i = 0; i < 4; ++i)
#pragma unroll
      for (int j = 0; j < 4; ++j)
        acc[i][j] = __builtin_amdgcn_mfma_f32_16x16x32_bf16(a_frag[i], b_frag[j], acc[i][j], 0, 0, 0);
    __syncthreads();
  }
#pragma unroll
  for (int i = 0; i < 4; ++i)
#pragma unroll
    for (int j = 0; j < 4; ++j)
#pragma unroll
      for (int r = 0; r < 4; ++r) {
        const int row = mw + 16 * i + q * 4 + r;
        const int col = nw + 16 * j + lrow;
        hg[(size_t)(gbase + row) * F_DIM + n0 + col] = f2b(gelu_exact(acc[i][j][r]));
      }
}

// ---------------- GEMM2: out[tok] += coef * (Hg @ W2t^T), split-K=2 ----------------
__global__ __launch_bounds__(256) void gemm2_k(const short* __restrict__ hg,
                                               const short* __restrict__ w2t,
                                               const int* __restrict__ meta,
                                               const int* __restrict__ tok,
                                               const float* __restrict__ coefv,
                                               float* __restrict__ out) {
  const int slot = blockIdx.y;
  if (slot >= meta[OFF_NT]) return;
  const int e = meta[OFF_SCHED_E + slot];
  const int gbase = meta[OFF_SCHED_G + slot];
  const int n0 = blockIdx.x * 128;
  const int kbase = blockIdx.z * (F_DIM / 2);

  __shared__ short As[128 * BK];
  __shared__ short Bs[128 * BK];

  const int tid = threadIdx.x;
  const int w = tid >> 6, l = tid & 63;
  const int mw = (w & 1) * 64, nw = (w >> 1) * 64;
  const int lrow = l & 15, q = l >> 4;

  const int srow = l >> 2;
  const int sk = (l & 3) * 8;
  const short* ag0 = hg + (size_t)(gbase + w * 32 + srow) * F_DIM + kbase + sk;
  const short* ag1 = ag0 + 16 * F_DIM;
  const short* bg0 = w2t + (size_t)(e * H_DIM + n0 + w * 32 + srow) * F_DIM + kbase + sk;
  const short* bg1 = bg0 + 16 * F_DIM;
  short* al0 = &As[(w * 32) * BK];
  short* al1 = &As[(w * 32 + 16) * BK];
  short* bl0 = &Bs[(w * 32) * BK];
  short* bl1 = &Bs[(w * 32 + 16) * BK];

  float4v acc[4][4] = {};

  for (int k0 = 0; k0 < F_DIM / 2; k0 += BK) {
    gl_lds16(ag0 + k0, al0);
    gl_lds16(ag1 + k0, al1);
    gl_lds16(bg0 + k0, bl0);
    gl_lds16(bg1 + k0, bl1);
    __syncthreads();
    short8 a_frag[4], b_frag[4];
#pragma unroll
    for (int i = 0; i < 4; ++i) a_frag[i] = *(const short8*)&As[(mw + 16 * i + lrow) * BK + q * 8];
#pragma unroll
    for (int j = 0; j < 4; ++j) b_frag[j] = *(const short8*)&Bs[(nw + 16 * j + lrow) * BK + q * 8];
#pragma unroll
    for (int i = 0; i < 4; ++i)
#pragma unroll
      for (int j = 0; j < 4; ++j)
        acc[i][j] = __builtin_amdgcn_mfma_f32_16x16x32_bf16(a_frag[i], b_frag[j], acc[i][j], 0, 0, 0);
    __syncthreads();
  }
#pragma unroll
  for (int i = 0; i < 4; ++i)
#pragma unroll
    for (int r = 0; r < 4; ++r) {
      const int row = mw + 16 * i + q * 4 + r;
      const int g = gbase + row;
      const int t = tok[g];
      if (t < 0) continue;
      const float cf = coefv[g];
#pragma unroll
      for (int j = 0; j < 4; ++j) {
        const int col = nw + 16 * j + lrow;
        atomicAdd(&out[(size_t)t * H_DIM + n0 + col], cf * acc[i][j][r]);
      }
    }
}

extern "C" void kernel_launch(void* const* d_in, const int* in_sizes, int n_in,
                              void* d_out, int out_size, void* d_ws, size_t ws_size,
                              hipStream_t stream) {
  const float* x  = (const float*)d_in[0];
  const float* rw = (const float*)d_in[1];
  const float* w1 = (const float*)d_in[2];
  const float* w2 = (const float*)d_in[3];
  float* out = (float*)d_out;
  float* logits = out + (size_t)T_TOK * H_DIM;

  char* ws = (char*)d_ws;
  int*   meta  = (int*)ws;
  int*   sel   = (int*)(ws + WS_SEL);
  int*   tok   = (int*)(ws + WS_TOK);
  float* coefv = (float*)(ws + WS_COEF);
  short* xg    = (short*)(ws + WS_XG);
  short* hg    = (short*)(ws + WS_HG);
  short* wt    = (short*)(ws + WS_WT);  // shared: W1t during gemm1, W2t during gemm2

  hipMemsetAsync(d_out, 0, (size_t)T_TOK * H_DIM * sizeof(float), stream);
  hipMemsetAsync(ws, 0, 768, stream);

  router_k<<<T_TOK / 4, 256, 0, stream>>>(x, rw, logits, meta, sel);
  schedule_k<<<1, 64, 0, stream>>>(meta, tok, coefv);
  scatter_k<<<(T_TOK * 2) / 256, 256, 0, stream>>>(sel, meta, tok, coefv);
  gather_x_k<<<(SEG_MAX * (H_DIM / 8)) / 256, 256, 0, stream>>>(x, tok, xg);
  conv_w1_k<<<dim3(EF_DIM / 64, H_DIM / 64), 256, 0, stream>>>(w1, wt);
  gemm1_k<<<dim3(F_DIM / 128, MAX_TILES), 256, 0, stream>>>(xg, wt, meta, hg);
  conv_w2_k<<<dim3(EF_DIM / 64, H_DIM / 64), 256, 0, stream>>>(w2, wt);
  gemm2_k<<<dim3(H_DIM / 128, MAX_TILES, 2), 256, 0, stream>>>(hg, wt, meta, tok, coefv, out);
}

// Round 3
// 527.938 us; speedup vs baseline: 1.0955x; 1.0561x over previous
//
#include <hip/hip_runtime.h>
#include <math.h>

// Problem constants: B=2,S=2048 -> T=4096, H=768, E=8, F=3072, K=2, BLOCK=16
#define T_TOK 4096
#define H_DIM 768
#define E_NUM 8
#define F_DIM 3072
#define EF_DIM 24576
#define BK 64
#define SEG_MAX 9216
#define MAX_TILES 72

// meta ints
#define OFF_COUNT   0
#define OFF_CURSOR  8
#define OFF_LAST    16
#define OFF_PAD     24
#define OFF_SEG     32
#define OFF_NT      40
#define OFF_TOTAL   41
#define OFF_SCHED_E 48
#define OFF_SCHED_G 120

// ws byte offsets
#define WS_SEL   768
#define WS_TOK   33536
#define WS_COEF  70400
#define WS_XG    107264ull     // bf16 Xg[9216][768]   = 14.16 MB
#define WS_HG    14263040ull   // bf16 Hg[9216][3072]  = 56.62 MB
#define WS_WT    70886144ull   // bf16 Wt (W1t then W2t, shared) = 37.75 MB

typedef __attribute__((ext_vector_type(8))) short short8;
typedef __attribute__((ext_vector_type(4))) float float4v;

__device__ __forceinline__ short f2b(float f) {
  union { float f; unsigned u; } v; v.f = f;
  unsigned r = v.u + 0x7FFFu + ((v.u >> 16) & 1u);  // RNE
  return (short)(r >> 16);
}
__device__ __forceinline__ float gelu_exact(float v) {
  return 0.5f * v * (1.0f + erff(v * 0.70710678118654752f));
}
__device__ __forceinline__ void gl_lds16(const void* g, void* l) {
  __builtin_amdgcn_global_load_lds(
      (const __attribute__((address_space(1))) void*)g,
      (__attribute__((address_space(3))) void*)l, 16, 0, 0);
}

// ---------------- Router ----------------
__global__ __launch_bounds__(256) void router_k(const float* __restrict__ x,
                                                const float* __restrict__ rw,
                                                float* __restrict__ logits_out,
                                                int* __restrict__ meta,
                                                int* __restrict__ sel) {
  __shared__ float rws[E_NUM * H_DIM];
  for (int i = threadIdx.x; i < E_NUM * H_DIM; i += 256) rws[i] = rw[i];
  __syncthreads();
  const int wid = threadIdx.x >> 6, lane = threadIdx.x & 63;
  const int t = blockIdx.x * 4 + wid;
  const float* xr = x + (size_t)t * H_DIM;
  double acc[E_NUM];
#pragma unroll
  for (int e = 0; e < E_NUM; ++e) acc[e] = 0.0;
  for (int i = 0; i < H_DIM / 64; ++i) {
    const int h = lane + 64 * i;
    const float xv = xr[h];
#pragma unroll
    for (int e = 0; e < E_NUM; ++e) acc[e] += (double)xv * (double)rws[e * H_DIM + h];
  }
#pragma unroll
  for (int e = 0; e < E_NUM; ++e)
    for (int off = 32; off; off >>= 1) acc[e] += __shfl_down(acc[e], off);
  if (lane == 0) {
    float lg[E_NUM];
#pragma unroll
    for (int e = 0; e < E_NUM; ++e) { lg[e] = (float)acc[e]; logits_out[t * E_NUM + e] = lg[e]; }
    int e0 = 0;
    for (int e = 1; e < E_NUM; ++e) if (lg[e] > lg[e0]) e0 = e;
    int e1 = -1;
    for (int e = 0; e < E_NUM; ++e) {
      if (e == e0) continue;
      if (e1 < 0 || lg[e] > lg[e1]) e1 = e;
    }
    sel[t * 2 + 0] = e0;
    sel[t * 2 + 1] = e1;
    atomicAdd(&meta[OFF_COUNT + e0], 1);
    atomicAdd(&meta[OFF_COUNT + e1], 1);
    atomicMax(&meta[OFF_LAST + e0], t * 2 + 0 + 1);
    atomicMax(&meta[OFF_LAST + e1], t * 2 + 1 + 1);
  }
}

// ---------------- Schedule ----------------
__global__ void schedule_k(int* __restrict__ meta, int* __restrict__ tok, float* __restrict__ coefv) {
  int cnt[E_NUM], seg[E_NUM];
  int s = 0;
#pragma unroll
  for (int e = 0; e < E_NUM; ++e) cnt[e] = meta[OFF_COUNT + e];
#pragma unroll
  for (int e = 0; e < E_NUM; ++e) { seg[e] = s; s += (cnt[e] + 127) & ~127; }
  if (threadIdx.x == 0) {
    int nt = 0;
    for (int e = 0; e < E_NUM; ++e) {
      meta[OFF_PAD + e] = (16 - (cnt[e] & 15)) & 15;
      meta[OFF_SEG + e] = seg[e];
      const int ru = (cnt[e] + 127) & ~127;
      for (int m = 0; m < ru; m += 128) {
        meta[OFF_SCHED_E + nt] = e;
        meta[OFF_SCHED_G + nt] = seg[e] + m;
        ++nt;
      }
    }
    meta[OFF_NT] = nt;
    meta[OFF_TOTAL] = s;
  }
  for (int e = 0; e < E_NUM; ++e) {
    const int ru = (cnt[e] + 127) & ~127;
    for (int p = cnt[e] + (int)threadIdx.x; p < ru; p += 64) {
      tok[seg[e] + p] = -1;
      coefv[seg[e] + p] = 0.0f;
    }
  }
  for (int p = s + (int)threadIdx.x; p < SEG_MAX; p += 64) {
    tok[p] = -1;
    coefv[p] = 0.0f;
  }
}

// ---------------- Scatter ----------------
__global__ __launch_bounds__(256) void scatter_k(const int* __restrict__ sel,
                                                 int* __restrict__ meta,
                                                 int* __restrict__ tok,
                                                 float* __restrict__ coefv) {
  const int a = blockIdx.x * 256 + threadIdx.x;
  const int e = sel[a];
  const int p = atomicAdd(&meta[OFF_CURSOR + e], 1);
  const int g = meta[OFF_SEG + e] + p;
  tok[g] = a >> 1;
  coefv[g] = (meta[OFF_LAST + e] == a + 1) ? (float)(1 + meta[OFF_PAD + e]) : 1.0f;
}

// ---------------- Gather x rows -> bf16 Xg ----------------
__global__ __launch_bounds__(256) void gather_x_k(const float* __restrict__ x,
                                                  const int* __restrict__ tok,
                                                  short* __restrict__ xg) {
  const int u = blockIdx.x * 256 + threadIdx.x;
  const int g = u / 96;
  const int c = (u - g * 96) * 8;
  const int t = tok[g];
  short8 v = {0, 0, 0, 0, 0, 0, 0, 0};
  if (t >= 0) {
    const float* src = x + (size_t)t * H_DIM + c;
    float4v f0 = *(const float4v*)src;
    float4v f1 = *(const float4v*)(src + 4);
    v[0] = f2b(f0[0]); v[1] = f2b(f0[1]); v[2] = f2b(f0[2]); v[3] = f2b(f0[3]);
    v[4] = f2b(f1[0]); v[5] = f2b(f1[1]); v[6] = f2b(f1[2]); v[7] = f2b(f1[3]);
  }
  *(short8*)&xg[(size_t)g * H_DIM + c] = v;
}

// ---------------- W1 [H][EF] f32 -> W1t [EF][H] bf16 ----------------
__global__ __launch_bounds__(256) void conv_w1_k(const float* __restrict__ w1, short* __restrict__ w1t) {
  __shared__ float tile[64][65];
  const int n0 = blockIdx.x * 64;
  const int h0 = blockIdx.y * 64;
  const int tid = threadIdx.x;
  const int rr = tid >> 4;
  const int cc = (tid & 15) * 4;
#pragma unroll
  for (int p = 0; p < 4; ++p) {
    const int r = p * 16 + rr;
    float4v f = *(const float4v*)(w1 + (size_t)(h0 + r) * EF_DIM + n0 + cc);
    tile[r][cc] = f[0]; tile[r][cc + 1] = f[1]; tile[r][cc + 2] = f[2]; tile[r][cc + 3] = f[3];
  }
  __syncthreads();
#pragma unroll
  for (int p = 0; p < 2; ++p) {
    const int item = p * 256 + tid;
    const int nl = item >> 3;
    const int u8 = (item & 7) * 8;
    short8 v;
#pragma unroll
    for (int j = 0; j < 8; ++j) v[j] = f2b(tile[u8 + j][nl]);
    *(short8*)(w1t + (size_t)(n0 + nl) * H_DIM + h0 + u8) = v;
  }
}

// ---------------- W2 [EF][H] f32 -> W2t [E][H][F] bf16 ----------------
__global__ __launch_bounds__(256) void conv_w2_k(const float* __restrict__ w2, short* __restrict__ w2t) {
  __shared__ float tile[64][65];
  const int k0 = blockIdx.x * 64;
  const int h0 = blockIdx.y * 64;
  const int e = k0 / F_DIM;
  const int f0 = k0 - e * F_DIM;
  const int tid = threadIdx.x;
  const int rr = tid >> 4;
  const int cc = (tid & 15) * 4;
#pragma unroll
  for (int p = 0; p < 4; ++p) {
    const int r = p * 16 + rr;
    float4v f = *(const float4v*)(w2 + (size_t)(k0 + r) * H_DIM + h0 + cc);
    tile[r][cc] = f[0]; tile[r][cc + 1] = f[1]; tile[r][cc + 2] = f[2]; tile[r][cc + 3] = f[3];
  }
  __syncthreads();
#pragma unroll
  for (int p = 0; p < 2; ++p) {
    const int item = p * 256 + tid;
    const int nl = item >> 3;
    const int u8 = (item & 7) * 8;
    short8 v;
#pragma unroll
    for (int j = 0; j < 8; ++j) v[j] = f2b(tile[u8 + j][nl]);
    *(short8*)(w2t + (size_t)(e * H_DIM + h0 + nl) * F_DIM + f0 + u8) = v;
  }
}

// Swizzled LDS tile: 128 rows x 64 halves (128 B/row). 16B chunk (r, c) lives at
// chunk slot c ^ (r & 7)  -> a quad's 16-row fragment read spreads across all
// 8 bank-sets (2-way aliasing only, which is free).
// global_load_lds dest is base + lane*16 (DMA requirement); the swizzle is
// applied to the per-lane GLOBAL chunk index instead (permutes within a 128 B
// row segment -> coalescing preserved).

// ---------------- GEMM1: Hg = gelu(Xg @ W1t^T) ----------------
__global__ __launch_bounds__(256) void gemm1_k(const short* __restrict__ xg,
                                               const short* __restrict__ w1t,
                                               const int* __restrict__ meta,
                                               short* __restrict__ hg) {
  const int slot = blockIdx.y;
  if (slot >= meta[OFF_NT]) return;
  const int e = meta[OFF_SCHED_E + slot];
  const int gbase = meta[OFF_SCHED_G + slot];
  const int n0 = blockIdx.x * 128;

  __shared__ short As[128 * BK];
  __shared__ short Bs[128 * BK];

  const int tid = threadIdx.x;
  const int w = tid >> 6, l = tid & 63;
  const int mw = (w & 1) * 64, nw = (w >> 1) * 64;
  const int lrow = l & 15, q = l >> 4;

  // staging: per issue i, wave w covers rows i*32+w*8 .. +8; lane l -> row +l>>3, chunk l&7
  const int srow = l >> 3;          // 0..7
  const int schunk = (l & 7) ^ srow;  // swizzled global chunk
  const short* agp[4];
  const short* bgp[4];
  short* alp[4];
  short* blp[4];
#pragma unroll
  for (int i = 0; i < 4; ++i) {
    const int r = i * 32 + w * 8 + srow;
    agp[i] = xg + (size_t)(gbase + r) * H_DIM + schunk * 8;
    bgp[i] = w1t + (size_t)(e * F_DIM + n0 + r) * H_DIM + schunk * 8;
    alp[i] = &As[(i * 32 + w * 8) * BK + l * 8];
    blp[i] = &Bs[(i * 32 + w * 8) * BK + l * 8];
  }
  // frag read swizzle: row = mw/nw + 16*i + lrow -> row&7 = lrow&7
  const int rsw = lrow & 7;

  float4v acc[4][4] = {};

  for (int k0 = 0; k0 < H_DIM; k0 += BK) {
#pragma unroll
    for (int i = 0; i < 4; ++i) gl_lds16(agp[i] + k0, alp[i]);
#pragma unroll
    for (int i = 0; i < 4; ++i) gl_lds16(bgp[i] + k0, blp[i]);
    __syncthreads();
#pragma unroll
    for (int s = 0; s < 2; ++s) {
      short8 a_frag[4], b_frag[4];
      const int csw = ((s * 4 + q) ^ rsw) * 8;
#pragma unroll
      for (int i = 0; i < 4; ++i) a_frag[i] = *(const short8*)&As[(mw + 16 * i + lrow) * BK + csw];
#pragma unroll
      for (int j = 0; j < 4; ++j) b_frag[j] = *(const short8*)&Bs[(nw + 16 * j + lrow) * BK + csw];
#pragma unroll
      for (int i = 0; i < 4; ++i)
#pragma unroll
        for (int j = 0; j < 4; ++j)
          acc[i][j] = __builtin_amdgcn_mfma_f32_16x16x32_bf16(a_frag[i], b_frag[j], acc[i][j], 0, 0, 0);
    }
    __syncthreads();
  }
#pragma unroll
  for (int i = 0; i < 4; ++i)
#pragma unroll
    for (int j = 0; j < 4; ++j)
#pragma unroll
      for (int r = 0; r < 4; ++r) {
        const int row = mw + 16 * i + q * 4 + r;
        const int col = nw + 16 * j + lrow;
        hg[(size_t)(gbase + row) * F_DIM + n0 + col] = f2b(gelu_exact(acc[i][j][r]));
      }
}

// ---------------- GEMM2: out[tok] += coef * (Hg @ W2t^T), split-K=2 ----------------
__global__ __launch_bounds__(256) void gemm2_k(const short* __restrict__ hg,
                                               const short* __restrict__ w2t,
                                               const int* __restrict__ meta,
                                               const int* __restrict__ tok,
                                               const float* __restrict__ coefv,
                                               float* __restrict__ out) {
  const int slot = blockIdx.y;
  if (slot >= meta[OFF_NT]) return;
  const int e = meta[OFF_SCHED_E + slot];
  const int gbase = meta[OFF_SCHED_G + slot];
  const int n0 = blockIdx.x * 128;
  const int kbase = blockIdx.z * (F_DIM / 2);

  __shared__ short As[128 * BK];
  __shared__ short Bs[128 * BK];

  const int tid = threadIdx.x;
  const int w = tid >> 6, l = tid & 63;
  const int mw = (w & 1) * 64, nw = (w >> 1) * 64;
  const int lrow = l & 15, q = l >> 4;

  const int srow = l >> 3;
  const int schunk = (l & 7) ^ srow;
  const short* agp[4];
  const short* bgp[4];
  short* alp[4];
  short* blp[4];
#pragma unroll
  for (int i = 0; i < 4; ++i) {
    const int r = i * 32 + w * 8 + srow;
    agp[i] = hg + (size_t)(gbase + r) * F_DIM + kbase + schunk * 8;
    bgp[i] = w2t + (size_t)(e * H_DIM + n0 + r) * F_DIM + kbase + schunk * 8;
    alp[i] = &As[(i * 32 + w * 8) * BK + l * 8];
    blp[i] = &Bs[(i * 32 + w * 8) * BK + l * 8];
  }
  const int rsw = lrow & 7;

  float4v acc[4][4] = {};

  for (int k0 = 0; k0 < F_DIM / 2; k0 += BK) {
#pragma unroll
    for (int i = 0; i < 4; ++i) gl_lds16(agp[i] + k0, alp[i]);
#pragma unroll
    for (int i = 0; i < 4; ++i) gl_lds16(bgp[i] + k0, blp[i]);
    __syncthreads();
#pragma unroll
    for (int s = 0; s < 2; ++s) {
      short8 a_frag[4], b_frag[4];
      const int csw = ((s * 4 + q) ^ rsw) * 8;
#pragma unroll
      for (int i = 0; i < 4; ++i) a_frag[i] = *(const short8*)&As[(mw + 16 * i + lrow) * BK + csw];
#pragma unroll
      for (int j = 0; j < 4; ++j) b_frag[j] = *(const short8*)&Bs[(nw + 16 * j + lrow) * BK + csw];
#pragma unroll
      for (int i = 0; i < 4; ++i)
#pragma unroll
        for (int j = 0; j < 4; ++j)
          acc[i][j] = __builtin_amdgcn_mfma_f32_16x16x32_bf16(a_frag[i], b_frag[j], acc[i][j], 0, 0, 0);
    }
    __syncthreads();
  }
#pragma unroll
  for (int i = 0; i < 4; ++i)
#pragma unroll
    for (int r = 0; r < 4; ++r) {
      const int row = mw + 16 * i + q * 4 + r;
      const int g = gbase + row;
      const int t = tok[g];
      if (t < 0) continue;
      const float cf = coefv[g];
#pragma unroll
      for (int j = 0; j < 4; ++j) {
        const int col = nw + 16 * j + lrow;
        atomicAdd(&out[(size_t)t * H_DIM + n0 + col], cf * acc[i][j][r]);
      }
    }
}

extern "C" void kernel_launch(void* const* d_in, const int* in_sizes, int n_in,
                              void* d_out, int out_size, void* d_ws, size_t ws_size,
                              hipStream_t stream) {
  const float* x  = (const float*)d_in[0];
  const float* rw = (const float*)d_in[1];
  const float* w1 = (const float*)d_in[2];
  const float* w2 = (const float*)d_in[3];
  float* out = (float*)d_out;
  float* logits = out + (size_t)T_TOK * H_DIM;

  char* ws = (char*)d_ws;
  int*   meta  = (int*)ws;
  int*   sel   = (int*)(ws + WS_SEL);
  int*   tok   = (int*)(ws + WS_TOK);
  float* coefv = (float*)(ws + WS_COEF);
  short* xg    = (short*)(ws + WS_XG);
  short* hg    = (short*)(ws + WS_HG);
  short* wt    = (short*)(ws + WS_WT);

  hipMemsetAsync(d_out, 0, (size_t)T_TOK * H_DIM * sizeof(float), stream);
  hipMemsetAsync(ws, 0, 768, stream);

  router_k<<<T_TOK / 4, 256, 0, stream>>>(x, rw, logits, meta, sel);
  schedule_k<<<1, 64, 0, stream>>>(meta, tok, coefv);
  scatter_k<<<(T_TOK * 2) / 256, 256, 0, stream>>>(sel, meta, tok, coefv);
  gather_x_k<<<(SEG_MAX * (H_DIM / 8)) / 256, 256, 0, stream>>>(x, tok, xg);
  conv_w1_k<<<dim3(EF_DIM / 64, H_DIM / 64), 256, 0, stream>>>(w1, wt);
  gemm1_k<<<dim3(F_DIM / 128, MAX_TILES), 256, 0, stream>>>(xg, wt, meta, hg);
  conv_w2_k<<<dim3(EF_DIM / 64, H_DIM / 64), 256, 0, stream>>>(w2, wt);
  gemm2_k<<<dim3(H_DIM / 128, MAX_TILES, 2), 256, 0, stream>>>(hg, wt, meta, tok, coefv, out);
}